// Round 3
// baseline (2650.283 us; speedup 1.0000x reference)
//
#include <hip/hip_runtime.h>
#include <hip/hip_bf16.h>

// InPlaceTTT on MI355X (gfx950).
// Pipeline (chunked over N for workspace safety):
//  k_colmean -> pooled col-sums of hidden
//  k_scal    -> alpha = sigmoid(mean@gw + gb), step = exp(lss)
//  k_convW   -> Wb = bf16(W) [V][D], WbT = bf16(W^T) [D][V]
//  k_zero    -> lsum = 0
//  k_z       -> z = alpha * h @ dB^T          (f32 exact)
//  k_o       -> out = h + z @ (alpha dA)^T    (f32 exact) ; ob = bf16(out)
//  per chunk:
//    k_gemm<0> -> P = exp(ob @ Wb^T) bf16 ; lsum[row] += rowsum (atomic)
//    k_gemm<1> -> G = P @ W / (lsum*N) - W[tgt]/N   (f32)
//  k_u       -> u = alpha * (G @ dA)
//  k_red_nr<0> -> gA partials (G,z) ; k_red_nr<1> -> gB partials (h,u)
//  k_final   -> A_new = alpha*dA - step*gA ; B_new = alpha*dB - step*gB
//
// GEMMs: m97-verified structure (128x128 tile, BK=64, 4 waves, 16x16x32 bf16
// MFMA, global_load_lds width=16). ~900 TF class. out/z/o kept f32-exact;
// bf16 only in the softmax-gradient path (gradient term is ~3e-5 of A_new;
// bf16 error on it lands ~1e-7 relative on outputs).
//
// Rasterization notes (audited, intentional):
//  GEMM1 SW=false: m fast (32 = 0 mod 8 -> each ob panel pinned to one XCD L2),
//    Wb panel shared by consecutive blocks.
//  GEMM2 SW=true: d fast (16 blocks share the 8.2MB P panel via L3; WbT 131MB
//    stays L3-resident across by-rows; P streams from HBM exactly once).

typedef __bf16 bf16;
typedef __attribute__((ext_vector_type(8))) __bf16 bf16x8;
typedef __attribute__((ext_vector_type(4))) __bf16 bf16x4;
typedef __attribute__((ext_vector_type(4))) float f32x4;

#define DEV static __device__ __forceinline__

static constexpr int Tn = 2048, Dm = 2048, Rr = 32, Vv = 32000;
static constexpr int Nn = 2 * Tn;                 // 4096 rows
static constexpr float INV_N = 1.0f / (float)Nn;
static constexpr int RED_CHUNKS = 16;             // k_red_nr grid.y
static constexpr int RED_NI = Nn / RED_CHUNKS;    // 256 rows per chunk

// Direct global->LDS (dwordx4). LDS dest is wave-uniform base + lane*16;
// our per-lane addresses follow exactly that pattern (t*16B within wave).
// AS cast via low-32-bits of generic LDS pointer (CK production pattern).
DEV void gload_lds16(const void* g, void* l) {
  __builtin_amdgcn_global_load_lds(
      (const __attribute__((address_space(1))) unsigned int*)(unsigned long long)g,
      (__attribute__((address_space(3))) unsigned int*)(unsigned int)(unsigned long long)l,
      16, 0, 0);
}

// ---------------------------------------------------------------- GEMM (m97 structure)
// C = A * B^T, operands [rows][K] (K-major) bf16. 128x128 tile, BK=64,
// 256 threads (4 waves 2x2), mfma_f32_16x16x32_bf16.
// EPI 0: Pout[m][n] = bf16(exp(acc)); atomicAdd(lsum[m], rowsum).
// EPI 1: Gout[m][c] = acc/(lsum[m]*N) - Wf[tgt[m]][c]/N.
// SW: swaps which block axis is M (see rasterization notes above).
template<int EPI, bool SW>
__global__ __launch_bounds__(256)
void k_gemm(const bf16* __restrict__ A, const bf16* __restrict__ B, int K,
            bf16* __restrict__ Pout, float* __restrict__ lsum,
            const float* __restrict__ Wf,
            const int* __restrict__ tgt, float* __restrict__ Gout)
{
  const int m0 = (SW ? blockIdx.y : blockIdx.x) * 128;
  const int n0 = (SW ? blockIdx.x : blockIdx.y) * 128;
  const int t = threadIdx.x;
  const int lane = t & 63;
  const int w = t >> 6;
  const int wr = (w >> 1) * 64;   // wave row offset in tile
  const int wc = (w & 1) * 64;    // wave col offset in tile

  __shared__ bf16 smem[2 * 128 * 64];           // As | Bs (32 KB)
  bf16* As = smem;
  bf16* Bs = smem + 128 * 64;

  f32x4 acc[4][4] = {};

  // staging: thread t loads 16B: row t/8 (+j*32), cols (t%8)*8..+8 of k-chunk
  const bf16* a0 = A + (size_t)(m0 + (t >> 3)) * K + (t & 7) * 8;
  const bf16* b0 = B + (size_t)(n0 + (t >> 3)) * K + (t & 7) * 8;
  bf16* asl = As + t * 8;
  bf16* bsl = Bs + t * 8;

  for (int kt = 0; kt < K; kt += 64) {
#pragma unroll
    for (int j = 0; j < 4; ++j) {
      gload_lds16(a0 + (size_t)j * 32 * K + kt, asl + j * 2048);
      gload_lds16(b0 + (size_t)j * 32 * K + kt, bsl + j * 2048);
    }
    __syncthreads();
#pragma unroll
    for (int kk = 0; kk < 2; ++kk) {
      bf16x8 af[4], bff[4];
#pragma unroll
      for (int i = 0; i < 4; ++i)
        af[i] = *(const bf16x8*)&As[(wr + i * 16 + (lane & 15)) * 64 + kk * 32 + (lane >> 4) * 8];
#pragma unroll
      for (int i = 0; i < 4; ++i)
        bff[i] = *(const bf16x8*)&Bs[(wc + i * 16 + (lane & 15)) * 64 + kk * 32 + (lane >> 4) * 8];
#pragma unroll
      for (int i = 0; i < 4; ++i)
#pragma unroll
        for (int j = 0; j < 4; ++j)
          acc[i][j] = __builtin_amdgcn_mfma_f32_16x16x32_bf16(af[i], bff[j], acc[i][j], 0, 0, 0);
    }
    __syncthreads();
  }

  const int cl = lane & 15;            // C/D: col = lane&15
  const int rl4 = (lane >> 4) * 4;     // row = (lane>>4)*4 + reg   [m89-verified]

  if (EPI == 0) {
    // repack exp(acc) through LDS [128][72] (16B-aligned rows) for 16B stores
    bf16* tile = smem;
#pragma unroll
    for (int i = 0; i < 4; ++i)
#pragma unroll
      for (int j = 0; j < 4; ++j)
#pragma unroll
        for (int rg = 0; rg < 4; ++rg)
          tile[(wr + i * 16 + rl4 + rg) * 72 + wc + j * 16 + cl] =
              (bf16)__expf(acc[i][j][rg]);
    __syncthreads();
    const int rr = t >> 1, ch = (t & 1) * 64;
    bf16* dst = Pout + (size_t)(m0 + rr) * Vv + n0 + ch;
    const bf16* srcr = tile + rr * 72 + ch;
    float s = 0.f;
#pragma unroll
    for (int j = 0; j < 8; ++j) {
      bf16x8 v = *(const bf16x8*)&srcr[j * 8];
      *(bf16x8*)&dst[j * 8] = v;
#pragma unroll
      for (int k = 0; k < 8; ++k) s += (float)v[k];
    }
    atomicAdd(&lsum[m0 + rr], s);      // 500 adds/row spread over ~600us: no contention
  } else {
#pragma unroll
    for (int i = 0; i < 4; ++i) {
      const int rbase = m0 + wr + i * 16 + rl4;
      float rl[4]; int tg[4];
#pragma unroll
      for (int rg = 0; rg < 4; ++rg) {
        rl[rg] = INV_N / lsum[rbase + rg];
        tg[rg] = tgt[rbase + rg];
      }
#pragma unroll
      for (int j = 0; j < 4; ++j) {
        const int c = n0 + wc + j * 16 + cl;
#pragma unroll
        for (int rg = 0; rg < 4; ++rg)
          Gout[(size_t)(rbase + rg) * Dm + c] =
              acc[i][j][rg] * rl[rg] - Wf[(size_t)tg[rg] * Dm + c] * INV_N;
      }
    }
  }
}

// ---------------------------------------------------------------- small kernels
__global__ __launch_bounds__(256) void k_zero(float* __restrict__ p, int n) {
  const int i = blockIdx.x * 256 + threadIdx.x;
  if (i < n) p[i] = 0.f;
}

__global__ __launch_bounds__(256) void k_colmean(const float* __restrict__ h,
                                                 float* __restrict__ pooled) {
  const int t = threadIdx.x;
  const int d = blockIdx.x * 32 + (t & 31);
  const int rp = t >> 5;
  float s = 0.f;
  for (int r = rp; r < Nn; r += 8) s += h[(size_t)r * Dm + d];
  __shared__ float red[8][32];
  red[rp][t & 31] = s;
  __syncthreads();
  if (t < 32) {
    float tot = 0.f;
#pragma unroll
    for (int j = 0; j < 8; ++j) tot += red[j][t];
    pooled[blockIdx.x * 32 + t] = tot;
  }
}

__global__ __launch_bounds__(256)
void k_scal(const float* __restrict__ pooled, const float* __restrict__ gw,
            const float* __restrict__ gb, const float* __restrict__ lss,
            float* __restrict__ scal) {
  const int t = threadIdx.x;
  float s = 0.f;
  for (int d = t; d < Dm; d += 256) s += pooled[d] * gw[d];
  __shared__ float red[256];
  red[t] = s; __syncthreads();
  for (int off = 128; off > 0; off >>= 1) {
    if (t < off) red[t] += red[t + off];
    __syncthreads();
  }
  if (t == 0) {
    const float x = red[0] * INV_N + gb[0];
    scal[0] = 1.0f / (1.0f + expf(-x));   // alpha
    scal[1] = expf(lss[0]);               // step
  }
}

// Wb = bf16(W) [V][D], WbT = bf16(W^T) [D][V] via 64x64 LDS tiles
__global__ __launch_bounds__(256)
void k_convW(const float* __restrict__ W, bf16* __restrict__ Wb,
             bf16* __restrict__ WbT) {
  __shared__ bf16 tile[64][72];
  const int t = threadIdx.x;
  const int v0 = blockIdx.x * 64, d0 = blockIdx.y * 64;
#pragma unroll
  for (int p = 0; p < 4; ++p) {
    const int v = (t >> 4) + p * 16, dc = (t & 15) * 4;
    float4 f = *(const float4*)&W[(size_t)(v0 + v) * Dm + d0 + dc];
    bf16 b0 = (bf16)f.x, b1 = (bf16)f.y, b2 = (bf16)f.z, b3 = (bf16)f.w;
    bf16x4 pk; pk[0] = b0; pk[1] = b1; pk[2] = b2; pk[3] = b3;
    *(bf16x4*)&Wb[(size_t)(v0 + v) * Dm + d0 + dc] = pk;
    tile[v][dc] = b0; tile[v][dc + 1] = b1; tile[v][dc + 2] = b2; tile[v][dc + 3] = b3;
  }
  __syncthreads();
  const int dr = t >> 2, c0 = (t & 3) * 16;
  bf16x8 x0, x1;
#pragma unroll
  for (int i = 0; i < 8; ++i) { x0[i] = tile[c0 + i][dr]; x1[i] = tile[c0 + 8 + i][dr]; }
  bf16* dst = WbT + (size_t)(d0 + dr) * Vv + v0 + c0;
  *(bf16x8*)&dst[0] = x0;
  *(bf16x8*)&dst[8] = x1;
}

// z = alpha * h @ dB^T (f32).  256 blocks x 16 rows; thread = 1 row x 2 r.
// h staged in padded LDS; dB (256KB) streamed from L2 via float4.
__global__ __launch_bounds__(256)
void k_z(const float* __restrict__ h, const float* __restrict__ dB,
         const float* __restrict__ scal, float* __restrict__ z) {
  __shared__ float hs[16][132];        // +4 pad: rows spread across banks
  const int t = threadIdx.x;
  const int n0 = blockIdx.x * 16;
  const int row = t >> 4;              // 16 rows
  const int rp = (t & 15) * 2;         // 2 r's per thread
  float a0 = 0.f, a1 = 0.f;
  for (int dc = 0; dc < Dm; dc += 128) {
#pragma unroll
    for (int j = 0; j < 2; ++j) {
      const int e = (t + j * 256) * 4;
      const int r = e >> 7, c = e & 127;
      *(float4*)&hs[r][c] = *(const float4*)&h[(size_t)(n0 + r) * Dm + dc + c];
    }
    __syncthreads();
    const float* b0p = dB + (size_t)rp * Dm + dc;
    const float* b1p = dB + (size_t)(rp + 1) * Dm + dc;
#pragma unroll 4
    for (int d4 = 0; d4 < 128; d4 += 4) {
      float4 hv = *(const float4*)&hs[row][d4];
      float4 b0 = *(const float4*)&b0p[d4];
      float4 b1 = *(const float4*)&b1p[d4];
      a0 += hv.x * b0.x + hv.y * b0.y + hv.z * b0.z + hv.w * b0.w;
      a1 += hv.x * b1.x + hv.y * b1.y + hv.z * b1.z + hv.w * b1.w;
    }
    __syncthreads();
  }
  const float alpha = scal[0];
  z[(size_t)(n0 + row) * Rr + rp] = a0 * alpha;
  z[(size_t)(n0 + row) * Rr + rp + 1] = a1 * alpha;
}

// out = h + z @ (alpha dA)^T (f32) ; ob = bf16(out)
__global__ __launch_bounds__(256)
void k_o(const float* __restrict__ h, const float* __restrict__ dA,
         const float* __restrict__ z, const float* __restrict__ scal,
         float* __restrict__ out, bf16* __restrict__ ob) {
  __shared__ float zs[64][36];
  __shared__ float sa[128][36];
  const int t = threadIdx.x;
  const int n0 = blockIdx.x * 64, d0 = blockIdx.y * 128;
  const float alpha = scal[0];
#pragma unroll
  for (int j = 0; j < 2; ++j) {
    const int e = (t + j * 256) * 4;
    *(float4*)&zs[e >> 5][e & 31] = *(const float4*)&z[(size_t)n0 * Rr + e];
  }
#pragma unroll
  for (int j = 0; j < 4; ++j) {
    const int e = (t + j * 256) * 4;
    const int r = e >> 5, c = e & 31;
    float4 f = *(const float4*)&dA[(size_t)(d0 + r) * Rr + c];
    f.x *= alpha; f.y *= alpha; f.z *= alpha; f.w *= alpha;
    *(float4*)&sa[r][c] = f;
  }
  __syncthreads();
  const int row = t >> 2, dq = (t & 3) * 32;
  float zr[32];
#pragma unroll
  for (int r = 0; r < 32; ++r) zr[r] = zs[row][r];
  const float* hrow = h + (size_t)(n0 + row) * Dm + d0 + dq;
  float* orow = out + (size_t)(n0 + row) * Dm + d0 + dq;
  bf16* obrow = ob + (size_t)(n0 + row) * Dm + d0 + dq;
#pragma unroll
  for (int d4 = 0; d4 < 32; d4 += 4) {
    float4 hv = *(const float4*)&hrow[d4];
    float o4[4];
#pragma unroll
    for (int k = 0; k < 4; ++k) {
      float s = 0.f;
#pragma unroll
      for (int r4 = 0; r4 < 32; r4 += 4) {       // float4 reads of sa row
        float4 sv = *(const float4*)&sa[dq + d4 + k][r4];
        s += zr[r4] * sv.x + zr[r4 + 1] * sv.y + zr[r4 + 2] * sv.z + zr[r4 + 3] * sv.w;
      }
      o4[k] = (&hv.x)[k] + s;
    }
    float4 ov; ov.x = o4[0]; ov.y = o4[1]; ov.z = o4[2]; ov.w = o4[3];
    *(float4*)&orow[d4] = ov;
    bf16x4 bv; bv[0] = (bf16)o4[0]; bv[1] = (bf16)o4[1]; bv[2] = (bf16)o4[2]; bv[3] = (bf16)o4[3];
    *(bf16x4*)&obrow[d4] = bv;
  }
}

// u = alpha * (G @ dA)   [N][R]
__global__ __launch_bounds__(256)
void k_u(const float* __restrict__ G, const float* __restrict__ dA,
         const float* __restrict__ scal, float* __restrict__ u) {
  __shared__ float gr[Dm];
  const int n = blockIdx.x, t = threadIdx.x;
#pragma unroll
  for (int j = 0; j < 2; ++j)
    *(float4*)&gr[(t + j * 256) * 4] = *(const float4*)&G[(size_t)n * Dm + (t + j * 256) * 4];
  __syncthreads();
  const int r = t & 31, jp = t >> 5;
  float s = 0.f;
  for (int i = 0; i < Dm / 8; ++i) {
    const int d = jp + i * 8;
    s += gr[d] * dA[(size_t)d * Rr + r];
  }
  __shared__ float red[8][32];
  red[jp][r] = s;
  __syncthreads();
  if (t < 32) {
    float tot = 0.f;
#pragma unroll
    for (int j = 0; j < 8; ++j) tot += red[j][t];
    u[(size_t)n * Rr + t] = tot * scal[0];
  }
}

// part[by] = sum_{n in chunk} X[n][d] * Y[n][r]; thread = 4d x 4r reg tile.
// TR=0: out d*R+r (gA [D][R]); TR=1: out r*D+d (gB [R][D])
template<bool TR>
__global__ __launch_bounds__(256)
void k_red_nr(const float* __restrict__ X, const float* __restrict__ Y,
              float* __restrict__ part) {
  __shared__ float ylds[RED_NI][32];   // 32 KB
  const int t = threadIdx.x;
  const int dg = (t & 31) * 4;
  const int rg = (t >> 5) * 4;
  const int d0 = blockIdx.x * 128;
  const int n0 = blockIdx.y * RED_NI;
#pragma unroll
  for (int j = 0; j < 8; ++j) {
    const int e = (t + j * 256) * 4;   // [0, 8192)
    *(float4*)&ylds[e >> 5][e & 31] = *(const float4*)&Y[(size_t)n0 * Rr + e];
  }
  __syncthreads();
  float acc[4][4] = {};
#pragma unroll 4
  for (int ni = 0; ni < RED_NI; ++ni) {
    float4 x4 = *(const float4*)&X[(size_t)(n0 + ni) * Dm + d0 + dg];
#pragma unroll
    for (int q = 0; q < 4; ++q) {
      const float yv = ylds[ni][rg + q];
      acc[0][q] += x4.x * yv;
      acc[1][q] += x4.y * yv;
      acc[2][q] += x4.z * yv;
      acc[3][q] += x4.w * yv;
    }
  }
  float* dst = part + (size_t)blockIdx.y * (Dm * Rr);
#pragma unroll
  for (int p = 0; p < 4; ++p)
#pragma unroll
    for (int q = 0; q < 4; ++q) {
      const int d = d0 + dg + p, r = rg + q;
      dst[TR ? (size_t)r * Dm + d : (size_t)d * Rr + r] = acc[p][q];
    }
}

__global__ __launch_bounds__(256)
void k_final(const float* __restrict__ dA, const float* __restrict__ dB,
             const float* __restrict__ gAp, const float* __restrict__ gBp,
             const float* __restrict__ scal,
             float* __restrict__ outA, float* __restrict__ outB) {
  const int i = blockIdx.x * 256 + threadIdx.x;
  const float alpha = scal[0], step = scal[1];
  float sa = 0.f, sb = 0.f;
#pragma unroll
  for (int j = 0; j < RED_CHUNKS; ++j) {
    sa += gAp[(size_t)j * Dm * Rr + i];
    sb += gBp[(size_t)j * Dm * Rr + i];
  }
  outA[i] = alpha * dA[i] - step * sa;
  outB[i] = alpha * dB[i] - step * sb;
}

// ---------------------------------------------------------------- launch
extern "C" void kernel_launch(void* const* d_in, const int* in_sizes, int n_in,
                              void* d_out, int out_size, void* d_ws, size_t ws_size,
                              hipStream_t stream) {
  const float* hidden = (const float*)d_in[0];
  const int* targets  = (const int*)d_in[1];
  const float* W      = (const float*)d_in[2];
  const float* dA     = (const float*)d_in[3];
  const float* dB     = (const float*)d_in[4];
  const float* gw     = (const float*)d_in[5];
  const float* gb     = (const float*)d_in[6];
  const float* lss    = (const float*)d_in[7];

  // fixed footprint (bytes, 256-aligned each)
  auto al = [](size_t b) { return (b + 255) & ~(size_t)255; };
  const size_t szWb  = al((size_t)Vv * Dm * 2);
  const size_t szWbT = al((size_t)Dm * Vv * 2);
  const size_t szOb  = al((size_t)Nn * Dm * 2);
  const size_t szG   = al((size_t)Nn * Dm * 4);
  const size_t szZ   = al((size_t)Nn * Rr * 4);
  const size_t szU   = szZ;
  const size_t szLs  = al((size_t)Nn * 4);
  const size_t szPl  = al((size_t)Dm * 4);
  const size_t szSc  = al(256);
  const size_t szPart= al((size_t)RED_CHUNKS * Dm * Rr * 4);
  const size_t fixed = szWb + szWbT + szOb + szG + szZ + szU + szLs + szPl + szSc + 2 * szPart;

  // chunk rows for P so the workspace fits (graph-safe: ws_size is constant)
  int Nc = Nn;
  while (Nc > 256 && fixed + al((size_t)Nc * Vv * 2) > ws_size) Nc >>= 1;
  if (fixed + al((size_t)Nc * Vv * 2) > ws_size) return;  // visible failure

  char* base = (char*)d_ws;
  size_t off = 0;
  auto alloc = [&](size_t bytes) -> void* { void* q = base + off; off += al(bytes); return q; };
  bf16*  Wb    = (bf16*)alloc((size_t)Vv * Dm * 2);
  bf16*  WbT   = (bf16*)alloc((size_t)Dm * Vv * 2);
  bf16*  ob    = (bf16*)alloc((size_t)Nn * Dm * 2);
  float* G     = (float*)alloc((size_t)Nn * Dm * 4);
  float* z     = (float*)alloc((size_t)Nn * Rr * 4);
  float* u     = (float*)alloc((size_t)Nn * Rr * 4);
  float* lsum  = (float*)alloc((size_t)Nn * 4);
  float* pooled= (float*)alloc((size_t)Dm * 4);
  float* scal  = (float*)alloc(256);
  float* gAp   = (float*)alloc((size_t)RED_CHUNKS * Dm * Rr * 4);
  float* gBp   = (float*)alloc((size_t)RED_CHUNKS * Dm * Rr * 4);
  bf16*  P     = (bf16*)alloc((size_t)Nc * Vv * 2);

  float* out  = (float*)d_out;
  float* outA = out + (size_t)Nn * Dm;
  float* outB = outA + (size_t)Dm * Rr;

  k_colmean<<<Dm / 32, 256, 0, stream>>>(hidden, pooled);
  k_scal<<<1, 256, 0, stream>>>(pooled, gw, gb, lss, scal);
  k_convW<<<dim3(Vv / 64, Dm / 64), 256, 0, stream>>>(W, Wb, WbT);
  k_zero<<<(Nn + 255) / 256, 256, 0, stream>>>(lsum, Nn);
  k_z<<<Nn / 16, 256, 0, stream>>>(hidden, dB, scal, z);
  k_o<<<dim3(Nn / 64, Dm / 128), 256, 0, stream>>>(hidden, dA, z, scal, out, ob);

  for (int ns = 0; ns < Nn; ns += Nc) {
    // P(chunk) = exp(ob_chunk @ Wb^T), fused row-sums into lsum
    k_gemm<0, false><<<dim3(Nc / 128, Vv / 128), 256, 0, stream>>>(
        ob + (size_t)ns * Dm, Wb, Dm, P, lsum + ns, nullptr, nullptr, nullptr);
    // G(chunk) = P @ W / (lsum*N) - W[tgt]/N
    k_gemm<1, true><<<dim3(Dm / 128, Nc / 128), 256, 0, stream>>>(
        P, WbT, Vv, nullptr, lsum + ns, W, targets + ns, G + (size_t)ns * Dm);
  }

  k_u<<<Nn, 256, 0, stream>>>(G, dA, scal, u);
  k_red_nr<false><<<dim3(Dm / 128, RED_CHUNKS), 256, 0, stream>>>(G, z, gAp);
  k_red_nr<true><<<dim3(Dm / 128, RED_CHUNKS), 256, 0, stream>>>(hidden, u, gBp);
  k_final<<<Dm * Rr / 256, 256, 0, stream>>>(dA, dB, gAp, gBp, scal, outA, outB);
}

// Round 4
// 2405.845 us; speedup vs baseline: 1.1016x; 1.1016x over previous
//
#include <hip/hip_runtime.h>
#include <hip/hip_bf16.h>

// InPlaceTTT on MI355X (gfx950).
// Round 4: GEMM1 (P = exp(ob @ Wb^T)) moved to the 256^2 8-wave counted-vmcnt
// structure (T2 swizzle + T4 counted waits + T5 setprio). GEMM2 unchanged (m97).
//
// Pipeline (chunked over N for workspace safety):
//  k_colmean -> pooled col-sums of hidden
//  k_scal    -> alpha = sigmoid(mean@gw + gb), step = exp(lss)
//  k_convW   -> Wb = bf16(W) [V][D], WbT = bf16(W^T) [D][V]
//  k_zero    -> lsum = 0
//  k_z       -> z = alpha * h @ dB^T          (f32 exact)
//  k_o       -> out = h + z @ (alpha dA)^T    (f32 exact) ; ob = bf16(out)
//  per chunk:
//    k_gemm1   -> P = exp(ob @ Wb^T) bf16 ; lsum[row] += rowsum (atomic)
//    k_gemm<1> -> G = P @ W / (lsum*N) - W[tgt]/N   (f32)
//  k_u       -> u = alpha * (G @ dA)
//  k_red_nr<0> -> gA partials (G,z) ; k_red_nr<1> -> gB partials (h,u)
//  k_final   -> A_new = alpha*dA - step*gA ; B_new = alpha*dB - step*gB

typedef __bf16 bf16;
typedef __attribute__((ext_vector_type(8))) __bf16 bf16x8;
typedef __attribute__((ext_vector_type(4))) __bf16 bf16x4;
typedef __attribute__((ext_vector_type(4))) float f32x4;

#define DEV static __device__ __forceinline__

static constexpr int Tn = 2048, Dm = 2048, Rr = 32, Vv = 32000;
static constexpr int Nn = 2 * Tn;                 // 4096 rows
static constexpr float INV_N = 1.0f / (float)Nn;
static constexpr int RED_CHUNKS = 16;             // k_red_nr grid.y
static constexpr int RED_NI = Nn / RED_CHUNKS;    // 256 rows per chunk

// Direct global->LDS (dwordx4). LDS dest must be wave-uniform base + lane*16.
DEV void gload_lds16(const void* g, void* l) {
  __builtin_amdgcn_global_load_lds(
      (const __attribute__((address_space(1))) unsigned int*)(unsigned long long)g,
      (__attribute__((address_space(3))) unsigned int*)(unsigned int)(unsigned long long)l,
      16, 0, 0);
}

// ---------------------------------------------------------------- GEMM1 (256^2, 8-wave, counted vmcnt)
// P = exp(A @ B^T) bf16, fused row-sums. A [M][K], B [V][K] bf16 K-major, K%64==0, K/64>=2.
// 512 threads = 8 waves (2M x 4N); per-wave output 128x64; BK=64; LDS 128KiB dbuf.
// T2 swizzle: LDS row of 8x16B blocks, block index XOR'd with (row&7). Inverse
// swizzle applied on the GLOBAL source (rule #21) so global_load_lds dest stays
// linear; ds_read applies the same XOR -> conflict-free b128 reads.
// Pipeline: tiles kt+1 (and kt+2 after first barrier) in flight; s_waitcnt
// vmcnt(8) (counted, never 0 mid-loop) + raw s_barrier; 2 barriers/K-tile.
__global__ __launch_bounds__(512, 2)
void k_gemm1(const bf16* __restrict__ A, const bf16* __restrict__ Bm, int K,
             bf16* __restrict__ Pout, float* __restrict__ lsum) {
  __shared__ __attribute__((aligned(16))) char smem[131072];
  const int t = threadIdx.x;
  const int lane = t & 63;
  const int fr = lane & 15;          // fragment row (A/B row within 16)
  const int fq = lane >> 4;          // 0..3
  const int w = t >> 6, wm = w >> 2, wn = w & 3;
  const int m0 = blockIdx.x * 256, n0 = blockIdx.y * 256;

  // staging: thread t covers rows sr + c*64 (c=0..3), 16B block sb of each 128B row
  const int sr = t >> 3;             // 0..63
  const int sb = t & 7;
  const int gbk = sb ^ (sr & 7);     // inverse-swizzled source block
  const bf16* aS = A + (size_t)(m0 + sr) * K + gbk * 8;
  const bf16* bS = Bm + (size_t)(n0 + sr) * K + gbk * 8;
  char* aD = smem + sr * 128 + sb * 16;           // linear LDS dest (base+lane*16 per wave)
  char* bD = smem + 32768 + sr * 128 + sb * 16;

  auto STAGE = [&](int db, int kt) {
    const bf16* ga = aS + (size_t)kt * 64;
    const bf16* gb2 = bS + (size_t)kt * 64;
    char* la = aD + db * 65536;
    char* lb = bD + db * 65536;
#pragma unroll
    for (int c = 0; c < 4; ++c) {
      gload_lds16(ga + (size_t)c * 64 * K, la + c * 8192);
      gload_lds16(gb2 + (size_t)c * 64 * K, lb + c * 8192);
    }
  };

  f32x4 acc[8][4] = {};

  STAGE(0, 0);
  STAGE(1, 1);
  asm volatile("s_waitcnt vmcnt(8)" ::: "memory");   // tile0 landed (per wave; barrier unions)
  __builtin_amdgcn_s_barrier();

  const int NT = K >> 6;
  int db = 0;
  for (int kt = 0; kt < NT; ++kt) {
    const char* bufA = smem + db * 65536;
    const char* bufB = bufA + 32768;
#pragma unroll
    for (int kk = 0; kk < 2; ++kk) {
      const int bp = ((kk * 4 + fq) ^ (fr & 7)) * 16;   // swizzled 16B block offset
      bf16x8 af[8], bfr[4];
#pragma unroll
      for (int i = 0; i < 8; ++i)
        af[i] = *(const bf16x8*)(bufA + (wm * 128 + i * 16 + fr) * 128 + bp);
#pragma unroll
      for (int j = 0; j < 4; ++j)
        bfr[j] = *(const bf16x8*)(bufB + (wn * 64 + j * 16 + fr) * 128 + bp);
      __builtin_amdgcn_s_setprio(1);
#pragma unroll
      for (int i = 0; i < 8; ++i)
#pragma unroll
        for (int j = 0; j < 4; ++j)
          acc[i][j] = __builtin_amdgcn_mfma_f32_16x16x32_bf16(af[i], bfr[j], acc[i][j], 0, 0, 0);
      __builtin_amdgcn_s_setprio(0);
    }
    __builtin_amdgcn_s_barrier();          // all waves done reading buf[db]
    if (kt + 2 < NT) {
      STAGE(db, kt + 2);                   // overwrite buf[db] with tile kt+2
      asm volatile("s_waitcnt vmcnt(8)" ::: "memory");  // tile kt+1 complete; kt+2 in flight
      __builtin_amdgcn_s_barrier();
    } else if (kt + 1 < NT) {
      asm volatile("s_waitcnt vmcnt(0)" ::: "memory");  // drain last tile
      __builtin_amdgcn_s_barrier();
    }
    db ^= 1;
  }

  // epilogue: exp + bf16, LDS repack in two 128-row passes, fused rowsum
  __builtin_amdgcn_s_barrier();
  bf16* tile = (bf16*)smem;                // [128][264] (67.6KB)
#pragma unroll
  for (int p = 0; p < 2; ++p) {
    if (wm == p) {
#pragma unroll
      for (int i = 0; i < 8; ++i)
#pragma unroll
        for (int j = 0; j < 4; ++j)
#pragma unroll
          for (int rg = 0; rg < 4; ++rg)
            tile[(i * 16 + fq * 4 + rg) * 264 + wn * 64 + j * 16 + fr] =
                (bf16)__expf(acc[i][j][rg]);
    }
    __builtin_amdgcn_s_barrier();
    {
      const int r = t >> 2, cb = (t & 3) * 64;
      const bf16* src = tile + r * 264 + cb;
      bf16* dst = Pout + (size_t)(m0 + p * 128 + r) * Vv + n0 + cb;
      float s = 0.f;
#pragma unroll
      for (int q = 0; q < 8; ++q) {
        bf16x8 v = *(const bf16x8*)&src[q * 8];
        *(bf16x8*)&dst[q * 8] = v;
#pragma unroll
        for (int e = 0; e < 8; ++e) s += (float)v[e];
      }
      s += __shfl_xor(s, 1);
      s += __shfl_xor(s, 2);
      if ((t & 3) == 0) atomicAdd(&lsum[m0 + p * 128 + r], s);
    }
    __builtin_amdgcn_s_barrier();
  }
}

// ---------------------------------------------------------------- GEMM (m97 structure) for GEMM2
// C = A * B^T, operands [rows][K] (K-major) bf16. 128x128 tile, BK=64,
// 256 threads (4 waves 2x2), mfma_f32_16x16x32_bf16.
// EPI 1: Gout[m][c] = acc/(lsum[m]*N) - Wf[tgt[m]][c]/N.
template<int EPI, bool SW>
__global__ __launch_bounds__(256)
void k_gemm(const bf16* __restrict__ A, const bf16* __restrict__ B, int K,
            bf16* __restrict__ Pout, float* __restrict__ lsum,
            const float* __restrict__ Wf,
            const int* __restrict__ tgt, float* __restrict__ Gout)
{
  const int m0 = (SW ? blockIdx.y : blockIdx.x) * 128;
  const int n0 = (SW ? blockIdx.x : blockIdx.y) * 128;
  const int t = threadIdx.x;
  const int lane = t & 63;
  const int w = t >> 6;
  const int wr = (w >> 1) * 64;
  const int wc = (w & 1) * 64;

  __shared__ bf16 smem[2 * 128 * 64];
  bf16* As = smem;
  bf16* Bs = smem + 128 * 64;

  f32x4 acc[4][4] = {};

  const bf16* a0 = A + (size_t)(m0 + (t >> 3)) * K + (t & 7) * 8;
  const bf16* b0 = B + (size_t)(n0 + (t >> 3)) * K + (t & 7) * 8;
  bf16* asl = As + t * 8;
  bf16* bsl = Bs + t * 8;

  for (int kt = 0; kt < K; kt += 64) {
#pragma unroll
    for (int j = 0; j < 4; ++j) {
      gload_lds16(a0 + (size_t)j * 32 * K + kt, asl + j * 2048);
      gload_lds16(b0 + (size_t)j * 32 * K + kt, bsl + j * 2048);
    }
    __syncthreads();
#pragma unroll
    for (int kk = 0; kk < 2; ++kk) {
      bf16x8 af[4], bff[4];
#pragma unroll
      for (int i = 0; i < 4; ++i)
        af[i] = *(const bf16x8*)&As[(wr + i * 16 + (lane & 15)) * 64 + kk * 32 + (lane >> 4) * 8];
#pragma unroll
      for (int i = 0; i < 4; ++i)
        bff[i] = *(const bf16x8*)&Bs[(wc + i * 16 + (lane & 15)) * 64 + kk * 32 + (lane >> 4) * 8];
#pragma unroll
      for (int i = 0; i < 4; ++i)
#pragma unroll
        for (int j = 0; j < 4; ++j)
          acc[i][j] = __builtin_amdgcn_mfma_f32_16x16x32_bf16(af[i], bff[j], acc[i][j], 0, 0, 0);
    }
    __syncthreads();
  }

  const int cl = lane & 15;
  const int rl4 = (lane >> 4) * 4;

#pragma unroll
  for (int i = 0; i < 4; ++i) {
    const int rbase = m0 + wr + i * 16 + rl4;
    float rl[4]; int tg[4];
#pragma unroll
    for (int rg = 0; rg < 4; ++rg) {
      rl[rg] = INV_N / lsum[rbase + rg];
      tg[rg] = tgt[rbase + rg];
    }
#pragma unroll
    for (int j = 0; j < 4; ++j) {
      const int c = n0 + wc + j * 16 + cl;
#pragma unroll
      for (int rg = 0; rg < 4; ++rg)
        Gout[(size_t)(rbase + rg) * Dm + c] =
            acc[i][j][rg] * rl[rg] - Wf[(size_t)tg[rg] * Dm + c] * INV_N;
    }
  }
}

// ---------------------------------------------------------------- small kernels
__global__ __launch_bounds__(256) void k_zero(float* __restrict__ p, int n) {
  const int i = blockIdx.x * 256 + threadIdx.x;
  if (i < n) p[i] = 0.f;
}

__global__ __launch_bounds__(256) void k_colmean(const float* __restrict__ h,
                                                 float* __restrict__ pooled) {
  const int t = threadIdx.x;
  const int d = blockIdx.x * 32 + (t & 31);
  const int rp = t >> 5;
  float s = 0.f;
  for (int r = rp; r < Nn; r += 8) s += h[(size_t)r * Dm + d];
  __shared__ float red[8][32];
  red[rp][t & 31] = s;
  __syncthreads();
  if (t < 32) {
    float tot = 0.f;
#pragma unroll
    for (int j = 0; j < 8; ++j) tot += red[j][t];
    pooled[blockIdx.x * 32 + t] = tot;
  }
}

__global__ __launch_bounds__(256)
void k_scal(const float* __restrict__ pooled, const float* __restrict__ gw,
            const float* __restrict__ gb, const float* __restrict__ lss,
            float* __restrict__ scal) {
  const int t = threadIdx.x;
  float s = 0.f;
  for (int d = t; d < Dm; d += 256) s += pooled[d] * gw[d];
  __shared__ float red[256];
  red[t] = s; __syncthreads();
  for (int off = 128; off > 0; off >>= 1) {
    if (t < off) red[t] += red[t + off];
    __syncthreads();
  }
  if (t == 0) {
    const float x = red[0] * INV_N + gb[0];
    scal[0] = 1.0f / (1.0f + expf(-x));   // alpha
    scal[1] = expf(lss[0]);               // step
  }
}

// Wb = bf16(W) [V][D], WbT = bf16(W^T) [D][V] via 64x64 LDS tiles
__global__ __launch_bounds__(256)
void k_convW(const float* __restrict__ W, bf16* __restrict__ Wb,
             bf16* __restrict__ WbT) {
  __shared__ bf16 tile[64][72];
  const int t = threadIdx.x;
  const int v0 = blockIdx.x * 64, d0 = blockIdx.y * 64;
#pragma unroll
  for (int p = 0; p < 4; ++p) {
    const int v = (t >> 4) + p * 16, dc = (t & 15) * 4;
    float4 f = *(const float4*)&W[(size_t)(v0 + v) * Dm + d0 + dc];
    bf16 b0 = (bf16)f.x, b1 = (bf16)f.y, b2 = (bf16)f.z, b3 = (bf16)f.w;
    bf16x4 pk; pk[0] = b0; pk[1] = b1; pk[2] = b2; pk[3] = b3;
    *(bf16x4*)&Wb[(size_t)(v0 + v) * Dm + d0 + dc] = pk;
    tile[v][dc] = b0; tile[v][dc + 1] = b1; tile[v][dc + 2] = b2; tile[v][dc + 3] = b3;
  }
  __syncthreads();
  const int dr = t >> 2, c0 = (t & 3) * 16;
  bf16x8 x0, x1;
#pragma unroll
  for (int i = 0; i < 8; ++i) { x0[i] = tile[c0 + i][dr]; x1[i] = tile[c0 + 8 + i][dr]; }
  bf16* dst = WbT + (size_t)(d0 + dr) * Vv + v0 + c0;
  *(bf16x8*)&dst[0] = x0;
  *(bf16x8*)&dst[8] = x1;
}

// z = alpha * h @ dB^T (f32)
__global__ __launch_bounds__(256)
void k_z(const float* __restrict__ h, const float* __restrict__ dB,
         const float* __restrict__ scal, float* __restrict__ z) {
  __shared__ float hs[16][132];
  const int t = threadIdx.x;
  const int n0 = blockIdx.x * 16;
  const int row = t >> 4;
  const int rp = (t & 15) * 2;
  float a0 = 0.f, a1 = 0.f;
  for (int dc = 0; dc < Dm; dc += 128) {
#pragma unroll
    for (int j = 0; j < 2; ++j) {
      const int e = (t + j * 256) * 4;
      const int r = e >> 7, c = e & 127;
      *(float4*)&hs[r][c] = *(const float4*)&h[(size_t)(n0 + r) * Dm + dc + c];
    }
    __syncthreads();
    const float* b0p = dB + (size_t)rp * Dm + dc;
    const float* b1p = dB + (size_t)(rp + 1) * Dm + dc;
#pragma unroll 4
    for (int d4 = 0; d4 < 128; d4 += 4) {
      float4 hv = *(const float4*)&hs[row][d4];
      float4 b0 = *(const float4*)&b0p[d4];
      float4 b1 = *(const float4*)&b1p[d4];
      a0 += hv.x * b0.x + hv.y * b0.y + hv.z * b0.z + hv.w * b0.w;
      a1 += hv.x * b1.x + hv.y * b1.y + hv.z * b1.z + hv.w * b1.w;
    }
    __syncthreads();
  }
  const float alpha = scal[0];
  z[(size_t)(n0 + row) * Rr + rp] = a0 * alpha;
  z[(size_t)(n0 + row) * Rr + rp + 1] = a1 * alpha;
}

// out = h + z @ (alpha dA)^T (f32) ; ob = bf16(out)
__global__ __launch_bounds__(256)
void k_o(const float* __restrict__ h, const float* __restrict__ dA,
         const float* __restrict__ z, const float* __restrict__ scal,
         float* __restrict__ out, bf16* __restrict__ ob) {
  __shared__ float zs[64][36];
  __shared__ float sa[128][36];
  const int t = threadIdx.x;
  const int n0 = blockIdx.x * 64, d0 = blockIdx.y * 128;
  const float alpha = scal[0];
#pragma unroll
  for (int j = 0; j < 2; ++j) {
    const int e = (t + j * 256) * 4;
    *(float4*)&zs[e >> 5][e & 31] = *(const float4*)&z[(size_t)n0 * Rr + e];
  }
#pragma unroll
  for (int j = 0; j < 4; ++j) {
    const int e = (t + j * 256) * 4;
    const int r = e >> 5, c = e & 31;
    float4 f = *(const float4*)&dA[(size_t)(d0 + r) * Rr + c];
    f.x *= alpha; f.y *= alpha; f.z *= alpha; f.w *= alpha;
    *(float4*)&sa[r][c] = f;
  }
  __syncthreads();
  const int row = t >> 2, dq = (t & 3) * 32;
  float zr[32];
#pragma unroll
  for (int r = 0; r < 32; ++r) zr[r] = zs[row][r];
  const float* hrow = h + (size_t)(n0 + row) * Dm + d0 + dq;
  float* orow = out + (size_t)(n0 + row) * Dm + d0 + dq;
  bf16* obrow = ob + (size_t)(n0 + row) * Dm + d0 + dq;
#pragma unroll
  for (int d4 = 0; d4 < 32; d4 += 4) {
    float4 hv = *(const float4*)&hrow[d4];
    float o4[4];
#pragma unroll
    for (int k = 0; k < 4; ++k) {
      float s = 0.f;
#pragma unroll
      for (int r4 = 0; r4 < 32; r4 += 4) {
        float4 sv = *(const float4*)&sa[dq + d4 + k][r4];
        s += zr[r4] * sv.x + zr[r4 + 1] * sv.y + zr[r4 + 2] * sv.z + zr[r4 + 3] * sv.w;
      }
      o4[k] = (&hv.x)[k] + s;
    }
    float4 ov; ov.x = o4[0]; ov.y = o4[1]; ov.z = o4[2]; ov.w = o4[3];
    *(float4*)&orow[d4] = ov;
    bf16x4 bv; bv[0] = (bf16)o4[0]; bv[1] = (bf16)o4[1]; bv[2] = (bf16)o4[2]; bv[3] = (bf16)o4[3];
    *(bf16x4*)&obrow[d4] = bv;
  }
}

// u = alpha * (G @ dA)   [N][R]
__global__ __launch_bounds__(256)
void k_u(const float* __restrict__ G, const float* __restrict__ dA,
         const float* __restrict__ scal, float* __restrict__ u) {
  __shared__ float gr[Dm];
  const int n = blockIdx.x, t = threadIdx.x;
#pragma unroll
  for (int j = 0; j < 2; ++j)
    *(float4*)&gr[(t + j * 256) * 4] = *(const float4*)&G[(size_t)n * Dm + (t + j * 256) * 4];
  __syncthreads();
  const int r = t & 31, jp = t >> 5;
  float s = 0.f;
  for (int i = 0; i < Dm / 8; ++i) {
    const int d = jp + i * 8;
    s += gr[d] * dA[(size_t)d * Rr + r];
  }
  __shared__ float red[8][32];
  red[jp][r] = s;
  __syncthreads();
  if (t < 32) {
    float tot = 0.f;
#pragma unroll
    for (int j = 0; j < 8; ++j) tot += red[j][t];
    u[(size_t)n * Rr + t] = tot * scal[0];
  }
}

// part[by] = sum_{n in chunk} X[n][d] * Y[n][r]; thread = 4d x 4r reg tile.
template<bool TR>
__global__ __launch_bounds__(256)
void k_red_nr(const float* __restrict__ X, const float* __restrict__ Y,
              float* __restrict__ part) {
  __shared__ float ylds[RED_NI][32];
  const int t = threadIdx.x;
  const int dg = (t & 31) * 4;
  const int rg = (t >> 5) * 4;
  const int d0 = blockIdx.x * 128;
  const int n0 = blockIdx.y * RED_NI;
#pragma unroll
  for (int j = 0; j < 8; ++j) {
    const int e = (t + j * 256) * 4;
    *(float4*)&ylds[e >> 5][e & 31] = *(const float4*)&Y[(size_t)n0 * Rr + e];
  }
  __syncthreads();
  float acc[4][4] = {};
#pragma unroll 4
  for (int ni = 0; ni < RED_NI; ++ni) {
    float4 x4 = *(const float4*)&X[(size_t)(n0 + ni) * Dm + d0 + dg];
#pragma unroll
    for (int q = 0; q < 4; ++q) {
      const float yv = ylds[ni][rg + q];
      acc[0][q] += x4.x * yv;
      acc[1][q] += x4.y * yv;
      acc[2][q] += x4.z * yv;
      acc[3][q] += x4.w * yv;
    }
  }
  float* dst = part + (size_t)blockIdx.y * (Dm * Rr);
#pragma unroll
  for (int p = 0; p < 4; ++p)
#pragma unroll
    for (int q = 0; q < 4; ++q) {
      const int d = d0 + dg + p, r = rg + q;
      dst[TR ? (size_t)r * Dm + d : (size_t)d * Rr + r] = acc[p][q];
    }
}

__global__ __launch_bounds__(256)
void k_final(const float* __restrict__ dA, const float* __restrict__ dB,
             const float* __restrict__ gAp, const float* __restrict__ gBp,
             const float* __restrict__ scal,
             float* __restrict__ outA, float* __restrict__ outB) {
  const int i = blockIdx.x * 256 + threadIdx.x;
  const float alpha = scal[0], step = scal[1];
  float sa = 0.f, sb = 0.f;
#pragma unroll
  for (int j = 0; j < RED_CHUNKS; ++j) {
    sa += gAp[(size_t)j * Dm * Rr + i];
    sb += gBp[(size_t)j * Dm * Rr + i];
  }
  outA[i] = alpha * dA[i] - step * sa;
  outB[i] = alpha * dB[i] - step * sb;
}

// ---------------------------------------------------------------- launch
extern "C" void kernel_launch(void* const* d_in, const int* in_sizes, int n_in,
                              void* d_out, int out_size, void* d_ws, size_t ws_size,
                              hipStream_t stream) {
  const float* hidden = (const float*)d_in[0];
  const int* targets  = (const int*)d_in[1];
  const float* W      = (const float*)d_in[2];
  const float* dA     = (const float*)d_in[3];
  const float* dB     = (const float*)d_in[4];
  const float* gw     = (const float*)d_in[5];
  const float* gb     = (const float*)d_in[6];
  const float* lss    = (const float*)d_in[7];

  auto al = [](size_t b) { return (b + 255) & ~(size_t)255; };
  const size_t szWb  = al((size_t)Vv * Dm * 2);
  const size_t szWbT = al((size_t)Dm * Vv * 2);
  const size_t szOb  = al((size_t)Nn * Dm * 2);
  const size_t szG   = al((size_t)Nn * Dm * 4);
  const size_t szZ   = al((size_t)Nn * Rr * 4);
  const size_t szU   = szZ;
  const size_t szLs  = al((size_t)Nn * 4);
  const size_t szPl  = al((size_t)Dm * 4);
  const size_t szSc  = al(256);
  const size_t szPart= al((size_t)RED_CHUNKS * Dm * Rr * 4);
  const size_t fixed = szWb + szWbT + szOb + szG + szZ + szU + szLs + szPl + szSc + 2 * szPart;

  // chunk rows for P so the workspace fits (graph-safe: ws_size is constant);
  // floor 256 keeps Nc a multiple of 256 for the 256^2 GEMM1.
  int Nc = Nn;
  while (Nc > 256 && fixed + al((size_t)Nc * Vv * 2) > ws_size) Nc >>= 1;
  if (fixed + al((size_t)Nc * Vv * 2) > ws_size) return;  // visible failure

  char* base = (char*)d_ws;
  size_t off = 0;
  auto alloc = [&](size_t bytes) -> void* { void* q = base + off; off += al(bytes); return q; };
  bf16*  Wb    = (bf16*)alloc((size_t)Vv * Dm * 2);
  bf16*  WbT   = (bf16*)alloc((size_t)Dm * Vv * 2);
  bf16*  ob    = (bf16*)alloc((size_t)Nn * Dm * 2);
  float* G     = (float*)alloc((size_t)Nn * Dm * 4);
  float* z     = (float*)alloc((size_t)Nn * Rr * 4);
  float* u     = (float*)alloc((size_t)Nn * Rr * 4);
  float* lsum  = (float*)alloc((size_t)Nn * 4);
  float* pooled= (float*)alloc((size_t)Dm * 4);
  float* scal  = (float*)alloc(256);
  float* gAp   = (float*)alloc((size_t)RED_CHUNKS * Dm * Rr * 4);
  float* gBp   = (float*)alloc((size_t)RED_CHUNKS * Dm * Rr * 4);
  bf16*  P     = (bf16*)alloc((size_t)Nc * Vv * 2);

  float* out  = (float*)d_out;
  float* outA = out + (size_t)Nn * Dm;
  float* outB = outA + (size_t)Dm * Rr;

  k_colmean<<<Dm / 32, 256, 0, stream>>>(hidden, pooled);
  k_scal<<<1, 256, 0, stream>>>(pooled, gw, gb, lss, scal);
  k_convW<<<dim3(Vv / 64, Dm / 64), 256, 0, stream>>>(W, Wb, WbT);
  k_zero<<<(Nn + 255) / 256, 256, 0, stream>>>(lsum, Nn);
  k_z<<<Nn / 16, 256, 0, stream>>>(hidden, dB, scal, z);
  k_o<<<dim3(Nn / 64, Dm / 128), 256, 0, stream>>>(hidden, dA, z, scal, out, ob);

  for (int ns = 0; ns < Nn; ns += Nc) {
    // P(chunk) = exp(ob_chunk @ Wb^T), fused row-sums into lsum
    k_gemm1<<<dim3(Nc / 256, Vv / 256), 512, 0, stream>>>(
        ob + (size_t)ns * Dm, Wb, Dm, P, lsum + ns);
    // G(chunk) = P @ W / (lsum*N) - W[tgt]/N
    k_gemm<1, true><<<dim3(Dm / 128, Nc / 128), 256, 0, stream>>>(
        P, WbT, Vv, nullptr, lsum + ns, W, targets + ns, G + (size_t)ns * Dm);
  }

  k_u<<<Nn, 256, 0, stream>>>(G, dA, scal, u);
  k_red_nr<false><<<dim3(Dm / 128, RED_CHUNKS), 256, 0, stream>>>(G, z, gAp);
  k_red_nr<true><<<dim3(Dm / 128, RED_CHUNKS), 256, 0, stream>>>(hidden, u, gBp);
  k_final<<<Dm * Rr / 256, 256, 0, stream>>>(dA, dB, gAp, gBp, scal, outA, outB);
}

// Round 5
// 2309.381 us; speedup vs baseline: 1.1476x; 1.0418x over previous
//
#include <hip/hip_runtime.h>
#include <hip/hip_bf16.h>

// InPlaceTTT on MI355X (gfx950).
// Round 5: V-chunked producer-consumer GEMM1/GEMM2 ping-pong (P chunk stays
// L3-resident between the two), GEMM2 rewritten to the 8-wave 256x128
// counted-vmcnt structure. GEMM2's old m97 form was fetch-bound (1.7 GB/disp,
// 4.3x over-fetch from L3 thrash: P 262MB + WbT 131MB > 256MB L3).
//
// Pipeline:
//  k_colmean/k_scal -> alpha, step
//  k_convW   -> Wb = bf16(W) [V][D], WbT = bf16(W^T) [D][V]
//  k_zero    -> lsum = 0
//  k_z       -> z = alpha * h @ dB^T          (f32 exact)
//  k_o       -> out = h + z @ (alpha dA)^T    (f32 exact) ; ob = bf16(out)
//  per V-chunk c (VC=6400):
//    k_gemm1     -> P_c = exp(ob @ Wb_c^T) bf16 ; lsum += rowsum (atomic)
//    k_gemm2<m>  -> G (+)= P_c @ WbT_c ; last chunk: G = G/(lsum*N) - W[tgt]/N
//  k_u       -> u = alpha * (G @ dA)
//  k_red_nr<0> -> gA partials (G,z) ; k_red_nr<1> -> gB partials (h,u)
//  k_final   -> A_new = alpha*dA - step*gA ; B_new = alpha*dB - step*gB

typedef __bf16 bf16;
typedef __attribute__((ext_vector_type(8))) __bf16 bf16x8;
typedef __attribute__((ext_vector_type(4))) __bf16 bf16x4;
typedef __attribute__((ext_vector_type(4))) float f32x4;

#define DEV static __device__ __forceinline__

static constexpr int Tn = 2048, Dm = 2048, Rr = 32, Vv = 32000;
static constexpr int Nn = 2 * Tn;                 // 4096 rows
static constexpr float INV_N = 1.0f / (float)Nn;
static constexpr int RED_CHUNKS = 16;
static constexpr int RED_NI = Nn / RED_CHUNKS;

// Direct global->LDS (dwordx4). LDS dest must be wave-uniform base + lane*16.
DEV void gload_lds16(const void* g, void* l) {
  __builtin_amdgcn_global_load_lds(
      (const __attribute__((address_space(1))) unsigned int*)(unsigned long long)g,
      (__attribute__((address_space(3))) unsigned int*)(unsigned int)(unsigned long long)l,
      16, 0, 0);
}

// ---------------------------------------------------------------- GEMM1 (256^2, 8-wave, counted vmcnt)
// P = exp(A @ B^T) bf16 (row stride Pld), fused row-sums. A [M][K], B [*][K].
// 512 thr = 8 waves (2M x 4N); per-wave 128x64; BK=64; LDS 128KiB dbuf.
// T2 swizzle: 128B LDS row = 8x16B blocks, block ^= (row&7); inverse applied
// on the GLOBAL source so global_load_lds dest stays linear (rule #21).
__global__ __launch_bounds__(512, 2)
void k_gemm1(const bf16* __restrict__ A, const bf16* __restrict__ Bm, int K,
             bf16* __restrict__ Pout, int Pld, float* __restrict__ lsum) {
  __shared__ __attribute__((aligned(16))) char smem[131072];
  const int t = threadIdx.x;
  const int lane = t & 63;
  const int fr = lane & 15;
  const int fq = lane >> 4;
  const int w = t >> 6, wm = w >> 2, wn = w & 3;
  const int m0 = blockIdx.x * 256, n0 = blockIdx.y * 256;

  const int sr = t >> 3;             // 0..63
  const int sb = t & 7;
  const int gbk = sb ^ (sr & 7);     // inverse-swizzled source block
  const bf16* aS = A + (size_t)(m0 + sr) * K + gbk * 8;
  const bf16* bS = Bm + (size_t)(n0 + sr) * K + gbk * 8;
  char* aD = smem + sr * 128 + sb * 16;
  char* bD = smem + 32768 + sr * 128 + sb * 16;

  auto STAGE = [&](int db, int kt) {
    const bf16* ga = aS + (size_t)kt * 64;
    const bf16* gb2 = bS + (size_t)kt * 64;
    char* la = aD + db * 65536;
    char* lb = bD + db * 65536;
#pragma unroll
    for (int c = 0; c < 4; ++c) {
      gload_lds16(ga + (size_t)c * 64 * K, la + c * 8192);
      gload_lds16(gb2 + (size_t)c * 64 * K, lb + c * 8192);
    }
  };

  f32x4 acc[8][4] = {};

  STAGE(0, 0);
  STAGE(1, 1);
  asm volatile("s_waitcnt vmcnt(8)" ::: "memory");
  __builtin_amdgcn_s_barrier();

  const int NT = K >> 6;
  int db = 0;
  for (int kt = 0; kt < NT; ++kt) {
    const char* bufA = smem + db * 65536;
    const char* bufB = bufA + 32768;
#pragma unroll
    for (int kk = 0; kk < 2; ++kk) {
      const int bp = ((kk * 4 + fq) ^ (fr & 7)) * 16;
      bf16x8 af[8], bfr[4];
#pragma unroll
      for (int i = 0; i < 8; ++i)
        af[i] = *(const bf16x8*)(bufA + (wm * 128 + i * 16 + fr) * 128 + bp);
#pragma unroll
      for (int j = 0; j < 4; ++j)
        bfr[j] = *(const bf16x8*)(bufB + (wn * 64 + j * 16 + fr) * 128 + bp);
      __builtin_amdgcn_s_setprio(1);
#pragma unroll
      for (int i = 0; i < 8; ++i)
#pragma unroll
        for (int j = 0; j < 4; ++j)
          acc[i][j] = __builtin_amdgcn_mfma_f32_16x16x32_bf16(af[i], bfr[j], acc[i][j], 0, 0, 0);
      __builtin_amdgcn_s_setprio(0);
    }
    __builtin_amdgcn_s_barrier();
    if (kt + 2 < NT) {
      STAGE(db, kt + 2);
      asm volatile("s_waitcnt vmcnt(8)" ::: "memory");
      __builtin_amdgcn_s_barrier();
    } else if (kt + 1 < NT) {
      asm volatile("s_waitcnt vmcnt(0)" ::: "memory");
      __builtin_amdgcn_s_barrier();
    }
    db ^= 1;
  }

  // epilogue: exp + bf16, LDS repack in two 128-row passes, fused rowsum
  __builtin_amdgcn_s_barrier();
  bf16* tile = (bf16*)smem;                // [128][264]
#pragma unroll
  for (int p = 0; p < 2; ++p) {
    if (wm == p) {
#pragma unroll
      for (int i = 0; i < 8; ++i)
#pragma unroll
        for (int j = 0; j < 4; ++j)
#pragma unroll
          for (int rg = 0; rg < 4; ++rg)
            tile[(i * 16 + fq * 4 + rg) * 264 + wn * 64 + j * 16 + fr] =
                (bf16)__expf(acc[i][j][rg]);
    }
    __builtin_amdgcn_s_barrier();
    {
      const int r = t >> 2, cb = (t & 3) * 64;
      const bf16* src = tile + r * 264 + cb;
      bf16* dst = Pout + (size_t)(m0 + p * 128 + r) * Pld + n0 + cb;
      float s = 0.f;
#pragma unroll
      for (int q = 0; q < 8; ++q) {
        bf16x8 v = *(const bf16x8*)&src[q * 8];
        *(bf16x8*)&dst[q * 8] = v;
#pragma unroll
        for (int e = 0; e < 8; ++e) s += (float)v[e];
      }
      s += __shfl_xor(s, 1);
      s += __shfl_xor(s, 2);
      if ((t & 3) == 0) atomicAdd(&lsum[m0 + p * 128 + r], s);
    }
    __builtin_amdgcn_s_barrier();
  }
}

// ---------------------------------------------------------------- GEMM2 (256x128, 8-wave, counted vmcnt)
// Gacc (+)= A @ B^T where A = P chunk [Nn][K] (stride K), B = WbT+voff rows d
// (stride Bld=Vv). 512 thr = 8 waves (4m x 2d); per-wave 64x64; BK=64.
// MODE bit0: accumulate into existing G. MODE bit1: finalize
//   G = Gacc/(lsum*N) - Wf[tgt]/N  (lsum complete: last k_gemm1 precedes this).
template<int MODE>
__global__ __launch_bounds__(512, 2)
void k_gemm2(const bf16* __restrict__ A, int K,
             const bf16* __restrict__ Bw, int Bld,
             float* __restrict__ G, const float* __restrict__ lsum,
             const float* __restrict__ Wf, const int* __restrict__ tgt) {
  __shared__ __attribute__((aligned(16))) char smem[98304];   // 2 x (32KB A + 16KB B)
  const int t = threadIdx.x;
  const int lane = t & 63;
  const int fr = lane & 15, fq = lane >> 4;
  const int w = t >> 6, wm = w >> 1, wn = w & 1;
  const int m0 = blockIdx.x * 256, d0 = blockIdx.y * 128;

  const int sr = t >> 3, sb = t & 7;
  const int gbk = sb ^ (sr & 7);
  const bf16* aS = A + (size_t)(m0 + sr) * K + gbk * 8;
  const bf16* bS = Bw + (size_t)(d0 + sr) * Bld + gbk * 8;
  char* aD = smem + sr * 128 + sb * 16;
  char* bD = smem + 32768 + sr * 128 + sb * 16;

  auto STAGE = [&](int db, int kt) {
    char* la = aD + db * 49152;
    char* lb = bD + db * 49152;
#pragma unroll
    for (int c = 0; c < 4; ++c)
      gload_lds16(aS + (size_t)kt * 64 + (size_t)c * 64 * K, la + c * 8192);
#pragma unroll
    for (int c = 0; c < 2; ++c)
      gload_lds16(bS + (size_t)kt * 64 + (size_t)c * 64 * Bld, lb + c * 8192);
  };

  f32x4 acc[4][4] = {};
  STAGE(0, 0);
  STAGE(1, 1);
  asm volatile("s_waitcnt vmcnt(6)" ::: "memory");
  __builtin_amdgcn_s_barrier();

  const int NT = K >> 6;
  int db = 0;
  for (int kt = 0; kt < NT; ++kt) {
    const char* bufA = smem + db * 49152;
    const char* bufB = bufA + 32768;
#pragma unroll
    for (int kk = 0; kk < 2; ++kk) {
      const int bp = ((kk * 4 + fq) ^ (fr & 7)) * 16;
      bf16x8 af[4], bf4[4];
#pragma unroll
      for (int i = 0; i < 4; ++i)
        af[i] = *(const bf16x8*)(bufA + (wm * 64 + i * 16 + fr) * 128 + bp);
#pragma unroll
      for (int j = 0; j < 4; ++j)
        bf4[j] = *(const bf16x8*)(bufB + (wn * 64 + j * 16 + fr) * 128 + bp);
      __builtin_amdgcn_s_setprio(1);
#pragma unroll
      for (int i = 0; i < 4; ++i)
#pragma unroll
        for (int j = 0; j < 4; ++j)
          acc[i][j] = __builtin_amdgcn_mfma_f32_16x16x32_bf16(af[i], bf4[j], acc[i][j], 0, 0, 0);
      __builtin_amdgcn_s_setprio(0);
    }
    __builtin_amdgcn_s_barrier();
    if (kt + 2 < NT) {
      STAGE(db, kt + 2);
      asm volatile("s_waitcnt vmcnt(6)" ::: "memory");
      __builtin_amdgcn_s_barrier();
    } else if (kt + 1 < NT) {
      asm volatile("s_waitcnt vmcnt(0)" ::: "memory");
      __builtin_amdgcn_s_barrier();
    }
    db ^= 1;
  }

  // epilogue: (optional) accumulate, (optional) finalize
#pragma unroll
  for (int i = 0; i < 4; ++i) {
    const int m4 = m0 + wm * 64 + i * 16 + fq * 4;
    float rl[4]; int tg[4];
    if (MODE & 2) {
#pragma unroll
      for (int rg = 0; rg < 4; ++rg) {
        rl[rg] = INV_N / lsum[m4 + rg];
        tg[rg] = tgt[m4 + rg];
      }
    }
#pragma unroll
    for (int j = 0; j < 4; ++j) {
      const int d = d0 + wn * 64 + j * 16 + fr;
#pragma unroll
      for (int rg = 0; rg < 4; ++rg) {
        float v = acc[i][j][rg];
        float* gp = &G[(size_t)(m4 + rg) * Dm + d];
        if (MODE & 1) v += *gp;
        if (MODE & 2) v = v * rl[rg] - Wf[(size_t)tg[rg] * Dm + d] * INV_N;
        *gp = v;
      }
    }
  }
}

// ---------------------------------------------------------------- small kernels
__global__ __launch_bounds__(256) void k_zero(float* __restrict__ p, int n) {
  const int i = blockIdx.x * 256 + threadIdx.x;
  if (i < n) p[i] = 0.f;
}

__global__ __launch_bounds__(256) void k_colmean(const float* __restrict__ h,
                                                 float* __restrict__ pooled) {
  const int t = threadIdx.x;
  const int d = blockIdx.x * 32 + (t & 31);
  const int rp = t >> 5;
  float s = 0.f;
  for (int r = rp; r < Nn; r += 8) s += h[(size_t)r * Dm + d];
  __shared__ float red[8][32];
  red[rp][t & 31] = s;
  __syncthreads();
  if (t < 32) {
    float tot = 0.f;
#pragma unroll
    for (int j = 0; j < 8; ++j) tot += red[j][t];
    pooled[blockIdx.x * 32 + t] = tot;
  }
}

__global__ __launch_bounds__(256)
void k_scal(const float* __restrict__ pooled, const float* __restrict__ gw,
            const float* __restrict__ gb, const float* __restrict__ lss,
            float* __restrict__ scal) {
  const int t = threadIdx.x;
  float s = 0.f;
  for (int d = t; d < Dm; d += 256) s += pooled[d] * gw[d];
  __shared__ float red[256];
  red[t] = s; __syncthreads();
  for (int off = 128; off > 0; off >>= 1) {
    if (t < off) red[t] += red[t + off];
    __syncthreads();
  }
  if (t == 0) {
    const float x = red[0] * INV_N + gb[0];
    scal[0] = 1.0f / (1.0f + expf(-x));   // alpha
    scal[1] = expf(lss[0]);               // step
  }
}

// Wb = bf16(W) [V][D], WbT = bf16(W^T) [D][V] via 64x64 LDS tiles
__global__ __launch_bounds__(256)
void k_convW(const float* __restrict__ W, bf16* __restrict__ Wb,
             bf16* __restrict__ WbT) {
  __shared__ bf16 tile[64][72];
  const int t = threadIdx.x;
  const int v0 = blockIdx.x * 64, d0 = blockIdx.y * 64;
#pragma unroll
  for (int p = 0; p < 4; ++p) {
    const int v = (t >> 4) + p * 16, dc = (t & 15) * 4;
    float4 f = *(const float4*)&W[(size_t)(v0 + v) * Dm + d0 + dc];
    bf16 b0 = (bf16)f.x, b1 = (bf16)f.y, b2 = (bf16)f.z, b3 = (bf16)f.w;
    bf16x4 pk; pk[0] = b0; pk[1] = b1; pk[2] = b2; pk[3] = b3;
    *(bf16x4*)&Wb[(size_t)(v0 + v) * Dm + d0 + dc] = pk;
    tile[v][dc] = b0; tile[v][dc + 1] = b1; tile[v][dc + 2] = b2; tile[v][dc + 3] = b3;
  }
  __syncthreads();
  const int dr = t >> 2, c0 = (t & 3) * 16;
  bf16x8 x0, x1;
#pragma unroll
  for (int i = 0; i < 8; ++i) { x0[i] = tile[c0 + i][dr]; x1[i] = tile[c0 + 8 + i][dr]; }
  bf16* dst = WbT + (size_t)(d0 + dr) * Vv + v0 + c0;
  *(bf16x8*)&dst[0] = x0;
  *(bf16x8*)&dst[8] = x1;
}

// z = alpha * h @ dB^T (f32)
__global__ __launch_bounds__(256)
void k_z(const float* __restrict__ h, const float* __restrict__ dB,
         const float* __restrict__ scal, float* __restrict__ z) {
  __shared__ float hs[16][132];
  const int t = threadIdx.x;
  const int n0 = blockIdx.x * 16;
  const int row = t >> 4;
  const int rp = (t & 15) * 2;
  float a0 = 0.f, a1 = 0.f;
  for (int dc = 0; dc < Dm; dc += 128) {
#pragma unroll
    for (int j = 0; j < 2; ++j) {
      const int e = (t + j * 256) * 4;
      const int r = e >> 7, c = e & 127;
      *(float4*)&hs[r][c] = *(const float4*)&h[(size_t)(n0 + r) * Dm + dc + c];
    }
    __syncthreads();
    const float* b0p = dB + (size_t)rp * Dm + dc;
    const float* b1p = dB + (size_t)(rp + 1) * Dm + dc;
#pragma unroll 4
    for (int d4 = 0; d4 < 128; d4 += 4) {
      float4 hv = *(const float4*)&hs[row][d4];
      float4 b0 = *(const float4*)&b0p[d4];
      float4 b1 = *(const float4*)&b1p[d4];
      a0 += hv.x * b0.x + hv.y * b0.y + hv.z * b0.z + hv.w * b0.w;
      a1 += hv.x * b1.x + hv.y * b1.y + hv.z * b1.z + hv.w * b1.w;
    }
    __syncthreads();
  }
  const float alpha = scal[0];
  z[(size_t)(n0 + row) * Rr + rp] = a0 * alpha;
  z[(size_t)(n0 + row) * Rr + rp + 1] = a1 * alpha;
}

// out = h + z @ (alpha dA)^T (f32) ; ob = bf16(out)
__global__ __launch_bounds__(256)
void k_o(const float* __restrict__ h, const float* __restrict__ dA,
         const float* __restrict__ z, const float* __restrict__ scal,
         float* __restrict__ out, bf16* __restrict__ ob) {
  __shared__ float zs[64][36];
  __shared__ float sa[128][36];
  const int t = threadIdx.x;
  const int n0 = blockIdx.x * 64, d0 = blockIdx.y * 128;
  const float alpha = scal[0];
#pragma unroll
  for (int j = 0; j < 2; ++j) {
    const int e = (t + j * 256) * 4;
    *(float4*)&zs[e >> 5][e & 31] = *(const float4*)&z[(size_t)n0 * Rr + e];
  }
#pragma unroll
  for (int j = 0; j < 4; ++j) {
    const int e = (t + j * 256) * 4;
    const int r = e >> 5, c = e & 31;
    float4 f = *(const float4*)&dA[(size_t)(d0 + r) * Rr + c];
    f.x *= alpha; f.y *= alpha; f.z *= alpha; f.w *= alpha;
    *(float4*)&sa[r][c] = f;
  }
  __syncthreads();
  const int row = t >> 2, dq = (t & 3) * 32;
  float zr[32];
#pragma unroll
  for (int r = 0; r < 32; ++r) zr[r] = zs[row][r];
  const float* hrow = h + (size_t)(n0 + row) * Dm + d0 + dq;
  float* orow = out + (size_t)(n0 + row) * Dm + d0 + dq;
  bf16* obrow = ob + (size_t)(n0 + row) * Dm + d0 + dq;
#pragma unroll
  for (int d4 = 0; d4 < 32; d4 += 4) {
    float4 hv = *(const float4*)&hrow[d4];
    float o4[4];
#pragma unroll
    for (int k = 0; k < 4; ++k) {
      float s = 0.f;
#pragma unroll
      for (int r4 = 0; r4 < 32; r4 += 4) {
        float4 sv = *(const float4*)&sa[dq + d4 + k][r4];
        s += zr[r4] * sv.x + zr[r4 + 1] * sv.y + zr[r4 + 2] * sv.z + zr[r4 + 3] * sv.w;
      }
      o4[k] = (&hv.x)[k] + s;
    }
    float4 ov; ov.x = o4[0]; ov.y = o4[1]; ov.z = o4[2]; ov.w = o4[3];
    *(float4*)&orow[d4] = ov;
    bf16x4 bv; bv[0] = (bf16)o4[0]; bv[1] = (bf16)o4[1]; bv[2] = (bf16)o4[2]; bv[3] = (bf16)o4[3];
    *(bf16x4*)&obrow[d4] = bv;
  }
}

// u = alpha * (G @ dA)   [N][R]
__global__ __launch_bounds__(256)
void k_u(const float* __restrict__ G, const float* __restrict__ dA,
         const float* __restrict__ scal, float* __restrict__ u) {
  __shared__ float gr[Dm];
  const int n = blockIdx.x, t = threadIdx.x;
#pragma unroll
  for (int j = 0; j < 2; ++j)
    *(float4*)&gr[(t + j * 256) * 4] = *(const float4*)&G[(size_t)n * Dm + (t + j * 256) * 4];
  __syncthreads();
  const int r = t & 31, jp = t >> 5;
  float s = 0.f;
  for (int i = 0; i < Dm / 8; ++i) {
    const int d = jp + i * 8;
    s += gr[d] * dA[(size_t)d * Rr + r];
  }
  __shared__ float red[8][32];
  red[jp][r] = s;
  __syncthreads();
  if (t < 32) {
    float tot = 0.f;
#pragma unroll
    for (int j = 0; j < 8; ++j) tot += red[j][t];
    u[(size_t)n * Rr + t] = tot * scal[0];
  }
}

// part[by] = sum_{n in chunk} X[n][d] * Y[n][r]; thread = 4d x 4r reg tile.
template<bool TR>
__global__ __launch_bounds__(256)
void k_red_nr(const float* __restrict__ X, const float* __restrict__ Y,
              float* __restrict__ part) {
  __shared__ float ylds[RED_NI][32];
  const int t = threadIdx.x;
  const int dg = (t & 31) * 4;
  const int rg = (t >> 5) * 4;
  const int d0 = blockIdx.x * 128;
  const int n0 = blockIdx.y * RED_NI;
#pragma unroll
  for (int j = 0; j < 8; ++j) {
    const int e = (t + j * 256) * 4;
    *(float4*)&ylds[e >> 5][e & 31] = *(const float4*)&Y[(size_t)n0 * Rr + e];
  }
  __syncthreads();
  float acc[4][4] = {};
#pragma unroll 4
  for (int ni = 0; ni < RED_NI; ++ni) {
    float4 x4 = *(const float4*)&X[(size_t)(n0 + ni) * Dm + d0 + dg];
#pragma unroll
    for (int q = 0; q < 4; ++q) {
      const float yv = ylds[ni][rg + q];
      acc[0][q] += x4.x * yv;
      acc[1][q] += x4.y * yv;
      acc[2][q] += x4.z * yv;
      acc[3][q] += x4.w * yv;
    }
  }
  float* dst = part + (size_t)blockIdx.y * (Dm * Rr);
#pragma unroll
  for (int p = 0; p < 4; ++p)
#pragma unroll
    for (int q = 0; q < 4; ++q) {
      const int d = d0 + dg + p, r = rg + q;
      dst[TR ? (size_t)r * Dm + d : (size_t)d * Rr + r] = acc[p][q];
    }
}

__global__ __launch_bounds__(256)
void k_final(const float* __restrict__ dA, const float* __restrict__ dB,
             const float* __restrict__ gAp, const float* __restrict__ gBp,
             const float* __restrict__ scal,
             float* __restrict__ outA, float* __restrict__ outB) {
  const int i = blockIdx.x * 256 + threadIdx.x;
  const float alpha = scal[0], step = scal[1];
  float sa = 0.f, sb = 0.f;
#pragma unroll
  for (int j = 0; j < RED_CHUNKS; ++j) {
    sa += gAp[(size_t)j * Dm * Rr + i];
    sb += gBp[(size_t)j * Dm * Rr + i];
  }
  outA[i] = alpha * dA[i] - step * sa;
  outB[i] = alpha * dB[i] - step * sb;
}

// ---------------------------------------------------------------- launch
extern "C" void kernel_launch(void* const* d_in, const int* in_sizes, int n_in,
                              void* d_out, int out_size, void* d_ws, size_t ws_size,
                              hipStream_t stream) {
  const float* hidden = (const float*)d_in[0];
  const int* targets  = (const int*)d_in[1];
  const float* W      = (const float*)d_in[2];
  const float* dA     = (const float*)d_in[3];
  const float* dB     = (const float*)d_in[4];
  const float* gw     = (const float*)d_in[5];
  const float* gb     = (const float*)d_in[6];
  const float* lss    = (const float*)d_in[7];

  auto al = [](size_t b) { return (b + 255) & ~(size_t)255; };
  const size_t fixed =
      al((size_t)Vv * Dm * 2) + al((size_t)Dm * Vv * 2) + al((size_t)Nn * Dm * 2) +
      al((size_t)Nn * Dm * 4) + 2 * al((size_t)Nn * Rr * 4) + al((size_t)Nn * 4) +
      al((size_t)Dm * 4) + al((size_t)256) + 2 * al((size_t)RED_CHUNKS * Dm * Rr * 4);

  // V-chunk size: multiple of 256 dividing 32000; shrink if ws is tight.
  int VC = 6400;
  while (VC > 1600 && fixed + al((size_t)Nn * VC * 2) > ws_size) VC >>= 1;
  if (fixed + al((size_t)Nn * VC * 2) > ws_size) return;  // visible failure

  char* base = (char*)d_ws;
  size_t off = 0;
  auto alloc = [&](size_t bytes) -> void* { void* q = base + off; off += al(bytes); return q; };
  bf16*  Wb    = (bf16*)alloc((size_t)Vv * Dm * 2);
  bf16*  WbT   = (bf16*)alloc((size_t)Dm * Vv * 2);
  bf16*  ob    = (bf16*)alloc((size_t)Nn * Dm * 2);
  float* G     = (float*)alloc((size_t)Nn * Dm * 4);
  float* z     = (float*)alloc((size_t)Nn * Rr * 4);
  float* u     = (float*)alloc((size_t)Nn * Rr * 4);
  float* lsum  = (float*)alloc((size_t)Nn * 4);
  float* pooled= (float*)alloc((size_t)Dm * 4);
  float* scal  = (float*)alloc(256);
  float* gAp   = (float*)alloc((size_t)RED_CHUNKS * Dm * Rr * 4);
  float* gBp   = (float*)alloc((size_t)RED_CHUNKS * Dm * Rr * 4);
  bf16*  P     = (bf16*)alloc((size_t)Nn * VC * 2);

  float* out  = (float*)d_out;
  float* outA = out + (size_t)Nn * Dm;
  float* outB = outA + (size_t)Dm * Rr;

  k_colmean<<<Dm / 32, 256, 0, stream>>>(hidden, pooled);
  k_scal<<<1, 256, 0, stream>>>(pooled, gw, gb, lss, scal);
  k_convW<<<dim3(Vv / 64, Dm / 64), 256, 0, stream>>>(W, Wb, WbT);
  k_zero<<<(Nn + 255) / 256, 256, 0, stream>>>(lsum, Nn);
  k_z<<<Nn / 16, 256, 0, stream>>>(hidden, dB, scal, z);
  k_o<<<dim3(Nn / 64, Dm / 128), 256, 0, stream>>>(hidden, dA, z, scal, out, ob);

  const int nch = Vv / VC;
  for (int c = 0; c < nch; ++c) {
    // P = exp(ob @ Wb_c^T), fused row-sums into lsum
    k_gemm1<<<dim3(Nn / 256, VC / 256), 512, 0, stream>>>(
        ob, Wb + (size_t)c * VC * Dm, Dm, P, VC, lsum);
    // G (+)= P @ WbT_c ; finalize on last chunk
    const int mode = (c > 0 ? 1 : 0) | (c == nch - 1 ? 2 : 0);
    const dim3 g2(Nn / 256, Dm / 128);
    const bf16* Bw = WbT + (size_t)c * VC;
    if (mode == 0)
      k_gemm2<0><<<g2, 512, 0, stream>>>(P, VC, Bw, Vv, G, lsum, W, targets);
    else if (mode == 1)
      k_gemm2<1><<<g2, 512, 0, stream>>>(P, VC, Bw, Vv, G, lsum, W, targets);
    else if (mode == 2)
      k_gemm2<2><<<g2, 512, 0, stream>>>(P, VC, Bw, Vv, G, lsum, W, targets);
    else
      k_gemm2<3><<<g2, 512, 0, stream>>>(P, VC, Bw, Vv, G, lsum, W, targets);
  }

  k_u<<<Nn, 256, 0, stream>>>(G, dA, scal, u);
  k_red_nr<false><<<dim3(Dm / 128, RED_CHUNKS), 256, 0, stream>>>(G, z, gAp);
  k_red_nr<true><<<dim3(Dm / 128, RED_CHUNKS), 256, 0, stream>>>(hidden, u, gBp);
  k_final<<<Dm * Rr / 256, 256, 0, stream>>>(dA, dB, gAp, gBp, scal, outA, outB);
}